// Round 18
// baseline (141.339 us; speedup 1.0000x reference)
//
#include <hip/hip_runtime.h>
#include <hip/hip_bf16.h>

#define HH 96
#define WW 96
#define CC 128
#define C2 256
#define PLANE (HH*WW)          // 9216
#define NGRP 6                 // fallback offset-conv channel groups
#define GP 8                   // ic per group
#define NG 16                  // hr groups
#define KSG 72                 // k-slots per group (9 taps * 8 ic)
#define ROWS 13                // fallback deform staged rows per plane window
#define NPCHK (ROWS*WW)        // 1248 16B plane chunks per group
#define PCHK_PAD 1280          // padded chunk count (uniform 2 loads/thread)
#define HPX 48                 // deform3 half-row pixels

typedef __attribute__((ext_vector_type(8))) short bf16x8;
typedef __attribute__((ext_vector_type(4))) float f32x4;
typedef __attribute__((ext_vector_type(4))) unsigned int u32x4;

__device__ __forceinline__ int swz(int row, int byte_in_row) {
    return row * 128 + (byte_in_row ^ ((row & 7) << 4));
}

__device__ __forceinline__ void gload_lds16(const void* g, void* l) {
    __builtin_amdgcn_global_load_lds(
        (const __attribute__((address_space(1))) char*)g,
        (__attribute__((address_space(3))) char*)l, 16, 0, 0);
}

__device__ __forceinline__ unsigned pack2(float a, float b) {
    return (unsigned)__bfloat16_as_ushort(__float2bfloat16(a)) |
           ((unsigned)__bfloat16_as_ushort(__float2bfloat16(b)) << 16);
}

#define MFMA16(A,B,C) __builtin_amdgcn_mfma_f32_16x16x32_bf16((A),(B),(C),0,0,0)

// counted waits + raw barriers (T3/T4); sched_barrier per rule #18
#define VMW4() { asm volatile("s_waitcnt vmcnt(4)" ::: "memory"); __builtin_amdgcn_sched_barrier(0); }
#define VMW0() { asm volatile("s_waitcnt vmcnt(0)" ::: "memory"); __builtin_amdgcn_sched_barrier(0); }
#define LGKM0_BAR() { asm volatile("s_waitcnt lgkmcnt(0)" ::: "memory"); \
    __builtin_amdgcn_sched_barrier(0); __builtin_amdgcn_s_barrier(); \
    __builtin_amdgcn_sched_barrier(0); }
#define RAW_BAR() { __builtin_amdgcn_sched_barrier(0); __builtin_amdgcn_s_barrier(); \
    __builtin_amdgcn_sched_barrier(0); }

// ------------- fused prep: hr->hrbf, lr->lrbf, w_def->wpad, w_off->wop -------------
__global__ __launch_bounds__(256) void prep_kernel(
    const float* __restrict__ hr, const float* __restrict__ lr,
    const float* __restrict__ w_def, const float* __restrict__ w_off,
    unsigned short* __restrict__ hrbf, unsigned short* __restrict__ lrbf,
    unsigned short* __restrict__ wpad, unsigned short* __restrict__ wop)
{
    const int bid = blockIdx.x;
    const int tid = threadIdx.x;
    if (bid < 4608) {                       // cvt8 for hr (0..2303) / lr (2304..4607)
        const bool is_hr = bid < 2304;
        const float* src0 = is_hr ? hr : lr;
        unsigned short* o = is_hr ? hrbf : lrbf;
        int idx = (is_hr ? bid : bid - 2304) * 256 + tid;
        int hw = idx % PLANE;
        int t  = idx / PLANE;
        int g  = t & 15;
        int b  = t >> 4;
        const float* src = src0 + ((size_t)(b * CC + g * GP)) * PLANE + hw;
        unsigned pk[4];
#pragma unroll
        for (int j = 0; j < 4; ++j)
            pk[j] = pack2(src[(size_t)(2*j) * PLANE], src[(size_t)(2*j+1) * PLANE]);
        u32x4 v = {pk[0], pk[1], pk[2], pk[3]};
        *reinterpret_cast<u32x4*>(o + (size_t)idx * 8) = v;
    } else if (bid < 5184) {                // wcvt: 147456 elems
        int i = (bid - 4608) * 256 + tid;
        int oc = i / (NG * KSG);
        int r  = i - oc * (NG * KSG);
        int g  = r / KSG;
        int s  = r - g * KSG;
        int tap = s >> 3;
        int icoff = s & 7;
        wpad[i] = __bfloat16_as_ushort(__float2bfloat16(
            w_def[(size_t)(oc * CC + g * GP + icoff) * 9 + tap]));
    } else {                                // woffcvt: 73728 elems
        int i = (bid - 5184) * 256 + tid;
        int oc = i / (32 * KSG);
        int r  = i - oc * (32 * KSG);
        int g  = r / KSG;
        int s  = r - g * KSG;
        int tap = s >> 3;
        int icoff = s & 7;
        int c = g * 8 + icoff;
        float v = (oc < 18) ? w_off[(size_t)(oc * C2 + c) * 9 + tap] : 0.f;
        wop[i] = __bfloat16_as_ushort(__float2bfloat16(v));
    }
}

// ------------- standalone converts (fallback paths only) ---------------------------
__global__ __launch_bounds__(256) void wcvt_kernel(const float* __restrict__ w,
                                                   unsigned short* __restrict__ o)
{
    int i = blockIdx.x * 256 + threadIdx.x;
    if (i < CC * NG * KSG) {
        int oc = i / (NG * KSG);
        int r  = i - oc * (NG * KSG);
        int g  = r / KSG;
        int s  = r - g * KSG;
        int tap = s >> 3;
        int icoff = s & 7;
        o[i] = __bfloat16_as_ushort(__float2bfloat16(
            w[(size_t)(oc * CC + g * GP + icoff) * 9 + tap]));
    }
}

__global__ __launch_bounds__(256) void cvt8_kernel(const float* __restrict__ src0,
                                                   unsigned short* __restrict__ o)
{
    int idx = blockIdx.x * 256 + threadIdx.x;
    int hw = idx % PLANE;
    int t  = idx / PLANE;
    int g  = t & 15;
    int b  = t >> 4;
    const float* src = src0 + ((size_t)(b * CC + g * GP)) * PLANE + hw;
    unsigned pk[4];
#pragma unroll
    for (int j = 0; j < 4; ++j)
        pk[j] = pack2(src[(size_t)(2*j) * PLANE], src[(size_t)(2*j+1) * PLANE]);
    u32x4 v = {pk[0], pk[1], pk[2], pk[3]};
    *reinterpret_cast<u32x4*>(o + (size_t)idx * 8) = v;
}

// ------------- Kernel 1 (fallback): fp32 offset conv, partials into d_out ----------
__global__ __launch_bounds__(256) void offset_conv_kernel(
    const float* __restrict__ lr, const float* __restrict__ hr,
    const float* __restrict__ w_off, float* __restrict__ outp)
{
    __shared__ float tile[2][324];
    const int bid = blockIdx.x;
    const int q   = bid % NGRP;
    const int t   = bid / NGRP;
    const int b   = t / 36;
    const int rr  = t % 36;
    const int h0  = (rr / 6) * 16;
    const int w0  = (rr % 6) * 16;
    const int tid = threadIdx.x;
    const int py  = tid >> 4;
    const int px  = tid & 15;

    const int c0 = (C2 * q) / NGRP, c1 = (C2 * (q + 1)) / NGRP;
    const float* srcp = (q < 3) ? lr : hr;
    const int cofs = (q < 3) ? 0 : CC;

    int gy0 = h0 - 1 + tid / 18, gx0 = w0 - 1 + tid % 18;
    bool ok0 = (unsigned)gy0 < (unsigned)HH && (unsigned)gx0 < (unsigned)WW;
    int off0 = gy0 * WW + gx0;
    int j1 = tid + 256;
    int gy1 = h0 - 1 + j1 / 18, gx1 = w0 - 1 + j1 % 18;
    bool ok1 = (j1 < 324) && (unsigned)gy1 < (unsigned)HH && (unsigned)gx1 < (unsigned)WW;
    int off1 = gy1 * WW + gx1;

    float acc[18];
#pragma unroll
    for (int oc = 0; oc < 18; ++oc) acc[oc] = 0.f;

    const float* pl = srcp + (size_t)(b * CC + c0 - cofs) * PLANE;
    float p0 = ok0 ? pl[off0] : 0.f;
    float p1 = ok1 ? pl[off1] : 0.f;

    for (int c = c0; c < c1; ++c) {
        float* tb = tile[c & 1];
        tb[tid] = p0;
        if (j1 < 324) tb[j1] = p1;
        __syncthreads();
        if (c + 1 < c1) {
            const float* pn = srcp + (size_t)(b * CC + c + 1 - cofs) * PLANE;
            p0 = ok0 ? pn[off0] : 0.f;
            p1 = ok1 ? pn[off1] : 0.f;
        }
        float tv[9];
#pragma unroll
        for (int ky = 0; ky < 3; ++ky)
#pragma unroll
            for (int kx = 0; kx < 3; ++kx)
                tv[ky*3+kx] = tb[(py+ky)*18 + px + kx];
#pragma unroll
        for (int oc = 0; oc < 18; ++oc) {
            const float* wp = w_off + (size_t)(oc * C2 + c) * 9;
#pragma unroll
            for (int tap = 0; tap < 9; ++tap)
                acc[oc] = fmaf(wp[tap], tv[tap], acc[oc]);
        }
    }
#pragma unroll
    for (int oc = 0; oc < 18; ++oc)
        outp[((size_t)(b*CC + q*18 + oc)) * PLANE + (h0+py)*WW + (w0+px)] = acc[oc];
}

// ------------- Kernel 1': offset conv, 2 c-groups per iteration --------------------
__global__ __launch_bounds__(768, 6) void offset_mfma_kernel(
    const unsigned short* __restrict__ lrbf, const unsigned short* __restrict__ hrbf,
    const unsigned short* __restrict__ wop, const float* __restrict__ b_off,
    float* __restrict__ offw)
{
    __shared__ __align__(16) unsigned short planes[2][2][3*WW*8];  // dbuf x grp: 18.4KB
    __shared__ __align__(16) unsigned short wgt0[2][32*64];        // 8KB swz
    __shared__ __align__(16) unsigned short wgt1[2][32*8];         // 1KB
    __shared__ __align__(16) unsigned short samp0[2][WW*64];       // 24.6KB swz
    __shared__ __align__(16) unsigned short samp1[2][WW*8];        // 3KB

    const int rawb = blockIdx.x;
    const int bid  = (rawb & 7) * 48 + (rawb >> 3);   // XCD swizzle
    const int b    = bid / HH;
    const int h    = bid % HH;
    const int tid  = threadIdx.x;

    const int pri = tid / 96, ppx = tid - (tid / 96) * 96;
    const int prow = min(max(h - 1 + pri, 0), HH - 1);

    const int woc = tid / 9, wsl = tid % 9;
    float4 wv0, wv1;

#define ISSUE_P2(PAIR, PB) { \
    if (tid < 288) { \
        int gA_ = 2*(PAIR), gB_ = gA_ + 1; \
        const unsigned short* bA_ = (gA_ < 16 ? lrbf : hrbf); \
        const unsigned short* bB_ = (gB_ < 16 ? lrbf : hrbf); \
        gload_lds16(bA_ + ((size_t)(b*16 + (gA_ & 15)) * PLANE + prow*WW + ppx) * 8, \
                    (char*)planes[PB][0] + tid*16); \
        gload_lds16(bB_ + ((size_t)(b*16 + (gB_ & 15)) * PLANE + prow*WW + ppx) * 8, \
                    (char*)planes[PB][1] + tid*16); \
    } }
#define ISSUE_W2(PAIR) { \
    if (tid < 288) { \
        wv0 = *reinterpret_cast<const float4*>(wop + ((size_t)(woc*32 + 2*(PAIR)    ))*KSG + wsl*8); \
        wv1 = *reinterpret_cast<const float4*>(wop + ((size_t)(woc*32 + 2*(PAIR) + 1))*KSG + wsl*8); \
    } }
#define WRITE_W2() { \
    if (tid < 288) { \
        if (wsl < 8) { \
            *reinterpret_cast<float4*>((char*)wgt0[0] + swz(woc, wsl*16)) = wv0; \
            *reinterpret_cast<float4*>((char*)wgt0[1] + swz(woc, wsl*16)) = wv1; \
        } else { \
            *reinterpret_cast<float4*>((char*)wgt1[0] + woc*16) = wv0; \
            *reinterpret_cast<float4*>((char*)wgt1[1] + woc*16) = wv1; \
        } \
    } }

    const int tap1 = tid / WW, px1 = tid - (tid / WW) * WW;   // taps 0..7
    const int ky1 = tap1 / 3 - 1, kx1 = tap1 % 3 - 1;
    const int row1 = h + ky1, x1 = px1 + kx1;
    const bool ok1 = (unsigned)row1 < (unsigned)HH && (unsigned)x1 < (unsigned)WW;
    const int ro1 = ((ky1+1)*WW + x1) * 16;
    const int wr1 = px1*128 + ((tap1*16) ^ ((px1 & 7) << 4));
    const int x2 = tid + 1;                                    // item2: tap 8
    const bool ok2 = (tid < 96) && (h + 1 < HH) && (x2 < WW);
    const int ro2 = (2*WW + x2) * 16;
    const int wr2 = tid * 16;

    const int lane = tid & 63;
    const int wid  = tid >> 6;
    const int ocg  = wid / 6;          // 0..1
    const int pxg  = wid - ocg * 6;    // 0..5
    const int l15  = lane & 15;
    const int l4   = lane >> 4;
    const int rowA = ocg*16 + l15;
    const int rowB = pxg*16 + l15;
    const bf16x8 zf = {};

    f32x4 acc = (f32x4){0.f, 0.f, 0.f, 0.f};

#define MFMA_O2() { \
    _Pragma("unroll") \
    for (int q_ = 0; q_ < 2; ++q_) { \
        bf16x8 a0_ = *reinterpret_cast<const bf16x8*>((char*)wgt0[q_] + swz(rowA, l4*16)); \
        bf16x8 a1_ = *reinterpret_cast<const bf16x8*>((char*)wgt0[q_] + swz(rowA, 64 + l4*16)); \
        bf16x8 a2_ = *reinterpret_cast<const bf16x8*>((char*)wgt1[q_] + rowA*16); \
        if (l4) a2_ = zf; \
        bf16x8 b0_ = *reinterpret_cast<const bf16x8*>((char*)samp0[q_] + swz(rowB, l4*16)); \
        bf16x8 b1_ = *reinterpret_cast<const bf16x8*>((char*)samp0[q_] + swz(rowB, 64 + l4*16)); \
        bf16x8 b2_ = *reinterpret_cast<const bf16x8*>((char*)samp1[q_] + rowB*16); \
        acc = MFMA16(a0_, b0_, acc); \
        acc = MFMA16(a1_, b1_, acc); \
        acc = MFMA16(a2_, b2_, acc); \
    } }

    ISSUE_W2(0);
    ISSUE_P2(0, 0);
    __syncthreads();

    for (int p2 = 0; p2 < 16; ++p2) {
        const int sb = p2 & 1;
        WRITE_W2();
        if (p2 < 15) {
            ISSUE_W2(p2 + 1);
            ISSUE_P2(p2 + 1, sb ^ 1);
            VMW4();
        } else {
            VMW0();
        }
        RAW_BAR();
        {
            u32x4 vA = {0u, 0u, 0u, 0u}, vB = {0u, 0u, 0u, 0u};
            if (ok1) {
                vA = *reinterpret_cast<const u32x4*>((const char*)planes[sb][0] + ro1);
                vB = *reinterpret_cast<const u32x4*>((const char*)planes[sb][1] + ro1);
            }
            *reinterpret_cast<u32x4*>((char*)samp0[0] + wr1) = vA;
            *reinterpret_cast<u32x4*>((char*)samp0[1] + wr1) = vB;
            if (tid < 96) {
                u32x4 wA = {0u, 0u, 0u, 0u}, wB = {0u, 0u, 0u, 0u};
                if (ok2) {
                    wA = *reinterpret_cast<const u32x4*>((const char*)planes[sb][0] + ro2);
                    wB = *reinterpret_cast<const u32x4*>((const char*)planes[sb][1] + ro2);
                }
                *reinterpret_cast<u32x4*>((char*)samp1[0] + wr2) = wA;
                *reinterpret_cast<u32x4*>((char*)samp1[1] + wr2) = wB;
            }
        }
        LGKM0_BAR();
        __builtin_amdgcn_s_setprio(1);
        MFMA_O2();
        __builtin_amdgcn_s_setprio(0);
        RAW_BAR();
    }

#pragma unroll
    for (int r = 0; r < 4; ++r) {
        int oc = ocg*16 + l4*4 + r;
        if (oc < 18)
            offw[((size_t)(b*18 + oc)) * PLANE + h*WW + pxg*16 + l15] = acc[r] + b_off[oc];
    }
#undef ISSUE_P2
#undef ISSUE_W2
#undef WRITE_W2
#undef MFMA_O2
}

// ------------- Kernel 2': deform conv, direct-global gather, dbuf 1-barrier --------
// grid: 768 blocks (XCD-swizzled), 384 threads (6 waves: 2 ocg x 3 pxg)
__global__ __launch_bounds__(384, 5) void deform3_kernel(
    const unsigned short* __restrict__ hrbf, const unsigned short* __restrict__ wpad,
    const float* __restrict__ b_def, const float* __restrict__ offw,
    float* __restrict__ outp)
{
    __shared__ __align__(16) unsigned short wgt0[2][CC*64];    // 32KB swz
    __shared__ __align__(16) unsigned short wgt1[2][CC*8];     // 4KB
    __shared__ __align__(16) unsigned short samp0[2][HPX*64];  // 12KB swz
    __shared__ __align__(16) unsigned short samp1[2][HPX*8];   // 1.5KB
    __shared__ float bias_lds[CC];                             // 0.5KB   total ~50KB

    const int rawb = blockIdx.x;
    const int bid  = (rawb & 7) * 96 + (rawb >> 3);   // XCD swizzle (768%8==0)
    const int b    = bid / 192;
    const int t2   = bid % 192;
    const int h    = t2 >> 1;
    const int half = t2 & 1;
    const int px0  = half * HPX;
    const int tid  = threadIdx.x;

    // wgt staging: 1152 chunks over 384 threads = 3 each
    float4 wv0, wv1, wv2;
    const int c0 = tid,        w0oc = c0 / 9, w0s = c0 % 9;
    const int c1 = tid + 384,  w1oc = c1 / 9, w1s = c1 % 9;
    const int c2 = tid + 768,  w2oc = c2 / 9, w2s = c2 % 9;

#define ISSUE_WGT(G) { \
    wv0 = *reinterpret_cast<const float4*>(wpad + ((size_t)(w0oc*NG + (G))*KSG + w0s*8)); \
    wv1 = *reinterpret_cast<const float4*>(wpad + ((size_t)(w1oc*NG + (G))*KSG + w1s*8)); \
    wv2 = *reinterpret_cast<const float4*>(wpad + ((size_t)(w2oc*NG + (G))*KSG + w2s*8)); }
#define WRITE_WGT(SB) { \
    if (w0s < 8) *reinterpret_cast<float4*>((char*)wgt0[SB] + swz(w0oc, w0s*16)) = wv0; \
    else         *reinterpret_cast<float4*>((char*)wgt1[SB] + w0oc*16) = wv0; \
    if (w1s < 8) *reinterpret_cast<float4*>((char*)wgt0[SB] + swz(w1oc, w1s*16)) = wv1; \
    else         *reinterpret_cast<float4*>((char*)wgt1[SB] + w1oc*16) = wv1; \
    if (w2s < 8) *reinterpret_cast<float4*>((char*)wgt0[SB] + swz(w2oc, w2s*16)) = wv2; \
    else         *reinterpret_cast<float4*>((char*)wgt1[SB] + w2oc*16) = wv2; }

    // ---- prologue: issue wgt(0); geometry into REGISTERS (small, 384-thr blocks) --
    ISSUE_WGT(0);

    // item1: it = tid (taps 0..7, since 384 = 8*48) -> samp0
    float4 w1_; int o1a, o1b, o1c, o1d, wr1;
    {
        int tap = tid / HPX, px = tid - (tid / HPX) * HPX;
        int gx  = px0 + px;
        int hw  = h * WW + gx;
        float offy = offw[((size_t)(b*18 + 2*tap    )) * PLANE + hw];
        float offx = offw[((size_t)(b*18 + 2*tap + 1)) * PLANE + hw];
        float sy = (float)h  + (float)(tap/3 - 1) + offy;
        float sx = (float)gx + (float)(tap%3 - 1) + offx;
        float y0f = floorf(sy), x0f = floorf(sx);
        float dy = sy - y0f, dx = sx - x0f;
        int y0 = (int)y0f, x0 = (int)x0f;
        bool y0v = (unsigned)y0 < (unsigned)HH, y1v = (unsigned)(y0+1) < (unsigned)HH;
        bool x0v = (unsigned)x0 < (unsigned)WW, x1v = (unsigned)(x0+1) < (unsigned)WW;
        float ody = 1.f - dy, odx = 1.f - dx;
        w1_.x = (y0v && x0v) ? ody*odx : 0.f;
        w1_.y = (y0v && x1v) ? ody*dx  : 0.f;
        w1_.z = (y1v && x0v) ? dy*odx  : 0.f;
        w1_.w = (y1v && x1v) ? dy*dx   : 0.f;
        int ra = min(max(y0,0),HH-1)*WW,  rb = min(max(y0+1,0),HH-1)*WW;
        int xa = min(max(x0,0),WW-1),     xb = min(max(x0+1,0),WW-1);
        o1a = (ra+xa)*16; o1b = (ra+xb)*16; o1c = (rb+xa)*16; o1d = (rb+xb)*16;
        wr1 = px*128 + ((tap*16) ^ ((px & 7) << 4));
    }
    // item2: tid<48 -> tap 8, px=tid -> samp1
    const bool has2 = tid < HPX;
    float4 w2_; int o2a=0, o2b=0, o2c=0, o2d=0, wr2=0;
    if (has2) {
        int gx = px0 + tid;
        int hw = h * WW + gx;
        float offy = offw[((size_t)(b*18 + 16)) * PLANE + hw];
        float offx = offw[((size_t)(b*18 + 17)) * PLANE + hw];
        float sy = (float)h  + 1.f + offy;
        float sx = (float)gx + 1.f + offx;
        float y0f = floorf(sy), x0f = floorf(sx);
        float dy = sy - y0f, dx = sx - x0f;
        int y0 = (int)y0f, x0 = (int)x0f;
        bool y0v = (unsigned)y0 < (unsigned)HH, y1v = (unsigned)(y0+1) < (unsigned)HH;
        bool x0v = (unsigned)x0 < (unsigned)WW, x1v = (unsigned)(x0+1) < (unsigned)WW;
        float ody = 1.f - dy, odx = 1.f - dx;
        w2_.x = (y0v && x0v) ? ody*odx : 0.f;
        w2_.y = (y0v && x1v) ? ody*dx  : 0.f;
        w2_.z = (y1v && x0v) ? dy*odx  : 0.f;
        w2_.w = (y1v && x1v) ? dy*dx   : 0.f;
        int ra = min(max(y0,0),HH-1)*WW,  rb = min(max(y0+1,0),HH-1)*WW;
        int xa = min(max(x0,0),WW-1),     xb = min(max(x0+1,0),WW-1);
        o2a = (ra+xa)*16; o2b = (ra+xb)*16; o2c = (rb+xa)*16; o2d = (rb+xb)*16;
        wr2 = tid * 16;
    }
    if (tid < CC) bias_lds[tid] = b_def[tid];

    const unsigned short* gb = hrbf + (size_t)(b * NG) * PLANE * 8;

#define BUILD_G(G, SB) { \
    const char* gpl_ = (const char*)(gb + (size_t)(G) * PLANE * 8); \
    { \
        u32x4 q00 = *reinterpret_cast<const u32x4*>(gpl_ + o1a); \
        u32x4 q01 = *reinterpret_cast<const u32x4*>(gpl_ + o1b); \
        u32x4 q10 = *reinterpret_cast<const u32x4*>(gpl_ + o1c); \
        u32x4 q11 = *reinterpret_cast<const u32x4*>(gpl_ + o1d); \
        float sv[8]; \
        _Pragma("unroll") \
        for (int j = 0; j < 4; ++j) { \
            float a00 = __uint_as_float(q00[j] << 16), b00 = __uint_as_float(q00[j] & 0xffff0000u); \
            float a01 = __uint_as_float(q01[j] << 16), b01 = __uint_as_float(q01[j] & 0xffff0000u); \
            float a10 = __uint_as_float(q10[j] << 16), b10 = __uint_as_float(q10[j] & 0xffff0000u); \
            float a11 = __uint_as_float(q11[j] << 16), b11 = __uint_as_float(q11[j] & 0xffff0000u); \
            sv[2*j]   = fmaf(w1_.x, a00, fmaf(w1_.y, a01, fmaf(w1_.z, a10, w1_.w*a11))); \
            sv[2*j+1] = fmaf(w1_.x, b00, fmaf(w1_.y, b01, fmaf(w1_.z, b10, w1_.w*b11))); \
        } \
        u32x4 pv = {pack2(sv[0],sv[1]), pack2(sv[2],sv[3]), \
                    pack2(sv[4],sv[5]), pack2(sv[6],sv[7])}; \
        *reinterpret_cast<u32x4*>((char*)samp0[SB] + wr1) = pv; \
    } \
    if (has2) { \
        u32x4 q00 = *reinterpret_cast<const u32x4*>(gpl_ + o2a); \
        u32x4 q01 = *reinterpret_cast<const u32x4*>(gpl_ + o2b); \
        u32x4 q10 = *reinterpret_cast<const u32x4*>(gpl_ + o2c); \
        u32x4 q11 = *reinterpret_cast<const u32x4*>(gpl_ + o2d); \
        float sv[8]; \
        _Pragma("unroll") \
        for (int j = 0; j < 4; ++j) { \
            float a00 = __uint_as_float(q00[j] << 16), b00 = __uint_as_float(q00[j] & 0xffff0000u); \
            float a01 = __uint_as_float(q01[j] << 16), b01 = __uint_as_float(q01[j] & 0xffff0000u); \
            float a10 = __uint_as_float(q10[j] << 16), b10 = __uint_as_float(q10[j] & 0xffff0000u); \
            float a11 = __uint_as_float(q11[j] << 16), b11 = __uint_as_float(q11[j] & 0xffff0000u); \
            sv[2*j]   = fmaf(w2_.x, a00, fmaf(w2_.y, a01, fmaf(w2_.z, a10, w2_.w*a11))); \
            sv[2*j+1] = fmaf(w2_.x, b00, fmaf(w2_.y, b01, fmaf(w2_.z, b10, w2_.w*b11))); \
        } \
        u32x4 pv = {pack2(sv[0],sv[1]), pack2(sv[2],sv[3]), \
                    pack2(sv[4],sv[5]), pack2(sv[6],sv[7])}; \
        *reinterpret_cast<u32x4*>((char*)samp1[SB] + wr2) = pv; \
    } }

    const int lane = tid & 63;
    const int wid  = tid >> 6;        // 0..5
    const int ocg  = wid / 3;         // 0..1 (64 oc each)
    const int pxg  = wid - ocg * 3;   // 0..2 (16 px each)
    const int l15  = lane & 15;
    const int l4   = lane >> 4;

    f32x4 acc[4];
#pragma unroll
    for (int mf = 0; mf < 4; ++mf) acc[mf] = (f32x4){0.f, 0.f, 0.f, 0.f};

    const int rowB = pxg*16 + l15;    // 0..47
    const bf16x8 zf = {};

#define MFMA_G(SB) { \
    _Pragma("unroll") \
    for (int ks = 0; ks < 2; ++ks) { \
        int kb = ks*64 + l4*16; \
        bf16x8 bb = *reinterpret_cast<const bf16x8*>((char*)samp0[SB] + swz(rowB, kb)); \
        _Pragma("unroll") \
        for (int mf = 0; mf < 4; ++mf) { \
            bf16x8 aa = *reinterpret_cast<const bf16x8*>((char*)wgt0[SB] + swz(ocg*64 + mf*16 + l15, kb)); \
            acc[mf] = MFMA16(aa, bb, acc[mf]); \
        } \
    } \
    { \
        bf16x8 bb = *reinterpret_cast<const bf16x8*>((char*)samp1[SB] + rowB*16); \
        _Pragma("unroll") \
        for (int mf = 0; mf < 4; ++mf) { \
            bf16x8 aa = *reinterpret_cast<const bf16x8*>((char*)wgt1[SB] + (ocg*64 + mf*16 + l15)*16); \
            if (l4) aa = zf; \
            acc[mf] = MFMA16(aa, bb, acc[mf]); \
        } \
    } }

    // ---- pipeline prologue: stage group 0 into buffer 0 ----
    WRITE_WGT(0);                      // waits wv (compiler-counted)
    ISSUE_WGT(1);
    BUILD_G(0, 0);
    LGKM0_BAR();                       // bufs(0) published

    // ---- main loop: 1 barrier per group; BUILD(g+1) overlaps MFMA(g) -------------
    for (int g = 0; g < NG; ++g) {
        const int cur = g & 1;
        if (g + 1 < NG) {
            WRITE_WGT(cur ^ 1);        // wgt(g+1): regs from prev ISSUE_WGT
            if (g + 2 < NG) ISSUE_WGT(g + 2);
            BUILD_G(g + 1, cur ^ 1);   // gathers fly; disjoint buffer from MFMA(g)
        }
        __builtin_amdgcn_s_setprio(1);
        MFMA_G(cur);
        __builtin_amdgcn_s_setprio(0);
        LGKM0_BAR();                   // publish bufs(g+1); MFMA(g) reads done blockwide
    }

    // ---- epilogue ----
#pragma unroll
    for (int mf = 0; mf < 4; ++mf)
#pragma unroll
        for (int r = 0; r < 4; ++r) {
            int oc = ocg*64 + mf*16 + l4*4 + r;
            float bd = bias_lds[oc];
            outp[((size_t)(b*CC + oc)) * PLANE + h*WW + px0 + pxg*16 + l15] = acc[mf][r] + bd;
        }
#undef ISSUE_WGT
#undef WRITE_WGT
#undef BUILD_G
#undef MFMA_G
}

// ------------- Kernel 2 (fallback): deformable conv with LDS planes ----------------
template<bool HRBF, bool OFFWS>
__global__ __launch_bounds__(768, 6) void deform2_kernel(
    const float* __restrict__ hr, const unsigned short* __restrict__ hrbf,
    const float* __restrict__ b_off, const unsigned short* __restrict__ wpad,
    const float* __restrict__ b_def, const float* __restrict__ offw,
    float* __restrict__ outp)
{
    __shared__ __align__(16) unsigned short planes[2][PCHK_PAD*8];  // 2x20480B
    __shared__ __align__(16) unsigned short wgt0[CC*64];            // 16KB swz
    __shared__ __align__(16) unsigned short wgt1[CC*8];             // 2KB
    __shared__ __align__(16) unsigned short samp0[WW*64];           // 12KB swz
    __shared__ __align__(16) unsigned short samp1[WW*8];            // 1.5KB
    __shared__ __align__(8)  float2 geom[9*97];                     // 6984B
    __shared__ float bias_lds[CC];

    const int rawb = blockIdx.x;
    const int bid  = (rawb & 7) * 48 + (rawb >> 3);
    const int b    = bid / HH;
    const int h    = bid % HH;
    const int tid  = threadIdx.x;
    const int r0   = min(max(h - 6, 0), HH - ROWS);

    const float* hrb = hr + (size_t)b * CC * PLANE;

    float4 wv0, wv1;
    const int wc0oc = tid / 9, wc0s = tid % 9;
    const int wt2   = (tid < 384) ? tid + 768 : tid;
    const int wc1oc = wt2 / 9, wc1s = wt2 % 9;
    const int pc2   = (tid < 512) ? tid + 768 : tid;
    const int pcs   = min(pc2, NPCHK - 1);

#define ISSUE_WGT(G) { \
    wv0 = *reinterpret_cast<const float4*>(wpad + ((size_t)(wc0oc*NG + (G))*KSG + wc0s*8)); \
    wv1 = *reinterpret_cast<const float4*>(wpad + ((size_t)(wc1oc*NG + (G))*KSG + wc1s*8)); }
#define WRITE_WGT() { \
    if (wc0s < 8) *reinterpret_cast<float4*>((char*)wgt0 + swz(wc0oc, wc0s*16)) = wv0; \
    else          *reinterpret_cast<float4*>((char*)wgt1 + wc0oc*16) = wv0; \
    if (tid < 384) { \
        if (wc1s < 8) *reinterpret_cast<float4*>((char*)wgt0 + swz(wc1oc, wc1s*16)) = wv1; \
        else          *reinterpret_cast<float4*>((char*)wgt1 + wc1oc*16) = wv1; \
    } }

#define ISSUE_PLANES(G, PB) { \
    const unsigned short* src_ = hrbf + ((size_t)(b*NG + (G))*PLANE + r0*WW)*8; \
    gload_lds16(src_ + (size_t)tid*8, (char*)planes[PB] + tid*16); \
    gload_lds16(src_ + (size_t)pcs*8, (char*)planes[PB] + pc2*16); }

#define STAGE_DIRECT(G, PB) { \
    for (int p = tid; p < NPCHK; p += 768) { \
        int r_ = p / WW, x_ = p - (p / WW) * WW; \
        const float* s_ = hrb + (size_t)((G)*GP) * PLANE + (r0 + r_)*WW + x_; \
        unsigned pk_[4]; \
        _Pragma("unroll") \
        for (int j = 0; j < 4; ++j) \
            pk_[j] = pack2(s_[(size_t)(2*j)*PLANE], s_[(size_t)(2*j+1)*PLANE]); \
        u32x4 v_ = {pk_[0], pk_[1], pk_[2], pk_[3]}; \
        *reinterpret_cast<u32x4*>((char*)planes[PB] + p*16) = v_; \
    } }

    if (HRBF) ISSUE_PLANES(0, 0);
    ISSUE_WGT(0);

    for (int t = tid; t < 9 * WW; t += 768) {
        int tap = t / WW;
        int px  = t - tap * WW;
        int hw  = h * WW + px;
        float offy, offx;
        if (OFFWS) {
            offy = offw[((size_t)(b*18 + 2*tap    )) * PLANE + hw];
            offx = offw[((size_t)(b*18 + 2*tap + 1)) * PLANE + hw];
        } else {
            offy = b_off[2*tap]; offx = b_off[2*tap + 1];
#pragma unroll
            for (int q = 0; q < NGRP; ++q) {
                offy += outp[((size_t)(b*CC + q*18 + 2*tap    )) * PLANE + hw];
                offx += outp[((size_t)(b*CC + q*18 + 2*tap + 1)) * PLANE + hw];
            }
        }
        geom[tap*97 + px] = make_float2((float)h  + (float)(tap/3 - 1) + offy,
                                        (float)px + (float)(tap%3 - 1) + offx);
    }
    if (tid < CC) bias_lds[tid] = b_def[tid];
    if (!HRBF) STAGE_DIRECT(0, 0);
    __syncthreads();

    const int lane = tid & 63;
    const int wid  = tid >> 6;
    const int ocg4 = wid / 3;
    const int pxg  = wid - ocg4 * 3;
    const int l15  = lane & 15;
    const int l4   = lane >> 4;

    f32x4 acc[2][2];
#pragma unroll
    for (int mf = 0; mf < 2; ++mf)
#pragma unroll
        for (int nf = 0; nf < 2; ++nf)
            acc[mf][nf] = (f32x4){0.f, 0.f, 0.f, 0.f};

    const int rowA0 = ocg4*32 + l15, rowA1 = rowA0 + 16;
    const int rowB0 = pxg*32 + l15,  rowB1 = rowB0 + 16;
    const bf16x8 zf = {};

#define MFMA_G() { \
    bf16x8 a00_ = *reinterpret_cast<const bf16x8*>((char*)wgt0 + swz(rowA0, l4*16)); \
    bf16x8 a10_ = *reinterpret_cast<const bf16x8*>((char*)wgt0 + swz(rowA1, l4*16)); \
    bf16x8 a01_ = *reinterpret_cast<const bf16x8*>((char*)wgt0 + swz(rowA0, 64 + l4*16)); \
    bf16x8 a11_ = *reinterpret_cast<const bf16x8*>((char*)wgt0 + swz(rowA1, 64 + l4*16)); \
    bf16x8 a02_ = *reinterpret_cast<const bf16x8*>((char*)wgt1 + rowA0*16); \
    bf16x8 a12_ = *reinterpret_cast<const bf16x8*>((char*)wgt1 + rowA1*16); \
    if (l4) { a02_ = zf; a12_ = zf; } \
    const char* s0_ = (const char*)samp0; \
    const char* s1_ = (const char*)samp1; \
    bf16x8 b00_ = *reinterpret_cast<const bf16x8*>(s0_ + swz(rowB0, l4*16)); \
    bf16x8 b10_ = *reinterpret_cast<const bf16x8*>(s0_ + swz(rowB1, l4*16)); \
    bf16x8 b01_ = *reinterpret_cast<const bf16x8*>(s0_ + swz(rowB0, 64 + l4*16)); \
    bf16x8 b11_ = *reinterpret_cast<const bf16x8*>(s0_ + swz(rowB1, 64 + l4*16)); \
    bf16x8 b02_ = *reinterpret_cast<const bf16x8*>(s1_ + rowB0*16); \
    bf16x8 b12_ = *reinterpret_cast<const bf16x8*>(s1_ + rowB1*16); \
    acc[0][0] = MFMA16(a00_, b00_, acc[0][0]); \
    acc[0][1] = MFMA16(a00_, b10_, acc[0][1]); \
    acc[1][0] = MFMA16(a10_, b00_, acc[1][0]); \
    acc[1][1] = MFMA16(a10_, b10_, acc[1][1]); \
    acc[0][0] = MFMA16(a01_, b01_, acc[0][0]); \
    acc[0][1] = MFMA16(a01_, b11_, acc[0][1]); \
    acc[1][0] = MFMA16(a11_, b01_, acc[1][0]); \
    acc[1][1] = MFMA16(a11_, b11_, acc[1][1]); \
    acc[0][0] = MFMA16(a02_, b02_, acc[0][0]); \
    acc[0][1] = MFMA16(a02_, b12_, acc[0][1]); \
    acc[1][0] = MFMA16(a12_, b02_, acc[1][0]); \
    acc[1][1] = MFMA16(a12_, b12_, acc[1][1]); }

    for (int g = 0; g < NG; ++g) {
        const int pb = g & 1;
        WRITE_WGT();
        if (g < NG - 1) {
            ISSUE_WGT(g + 1);
            if (HRBF) { ISSUE_PLANES(g + 1, pb ^ 1); }
            else      { STAGE_DIRECT(g + 1, pb ^ 1); }
            if (HRBF) { VMW4(); }
        } else {
            if (HRBF) { VMW0(); }
        }
        for (int it = tid; it < 9 * WW; it += 768) {
            int tap = it / WW;
            int px  = it - tap * WW;
            float2 s2 = geom[tap*97 + px];
            float sy = s2.x, sx = s2.y;
            float y0f = floorf(sy), x0f = floorf(sx);
            float dy = sy - y0f, dx = sx - x0f;
            int y0 = (int)y0f, x0 = (int)x0f;
            bool y0v = (unsigned)y0       < (unsigned)HH;
            bool y1v = (unsigned)(y0 + 1) < (unsigned)HH;
            bool x0v = (unsigned)x0       < (unsigned)WW;
            bool x1v = (unsigned)(x0 + 1) < (unsigned)WW;
            float ody = 1.f - dy, odx = 1.f - dx;
            float w00 = (y0v && x0v) ? ody*odx : 0.f;
            float w01 = (y0v && x1v) ? ody*dx  : 0.f;
            float w10 = (y1v && x0v) ? dy*odx  : 0.f;
            float w11 = (y1v && x1v) ? dy*dx   : 0.f;
            int y0c = min(max(y0, 0), HH-1), y1c = min(max(y0+1, 0), HH-1);
            int x0c = min(max(x0, 0), WW-1), x1c = min(max(x0+1, 0), WW-1);
            float sv[GP];
            bool ng = (y0v && (unsigned)(y0 - r0) >= (unsigned)ROWS) ||
                      (y1v && (unsigned)(y1c - r0) >= (unsigned)ROWS);
            if (__builtin_expect(!ng, 1)) {
                int ra = min(max(y0c - r0, 0), ROWS-1);
                int rb = min(max(y1c - r0, 0), ROWS-1);
                const char* pbase = (const char*)planes[pb];
                u32x4 q00 = *reinterpret_cast<const u32x4*>(pbase + (ra*WW + x0c)*16);
                u32x4 q01 = *reinterpret_cast<const u32x4*>(pbase + (ra*WW + x1c)*16);
                u32x4 q10 = *reinterpret_cast<const u32x4*>(pbase + (rb*WW + x0c)*16);
                u32x4 q11 = *reinterpret_cast<const u32x4*>(pbase + (rb*WW + x1c)*16);
#pragma unroll
                for (int j = 0; j < 4; ++j) {
                    float a00 = __uint_as_float(q00[j] << 16), b00 = __uint_as_float(q00[j] & 0xffff0000u);
                    float a01 = __uint_as_float(q01[j] << 16), b01 = __uint_as_float(q01[j] & 0xffff0000u);
                    float a10 = __uint_as_float(q10[j] << 16), b10 = __uint_as_float(q10[j] & 0xffff0000u);
                    float a11 = __uint_as_float(q11[j] << 16), b11 = __uint_as_float(q11[j] & 0xffff0000u);
                    sv[2*j]   = fmaf(w00, a00, fmaf(w01, a01, fmaf(w10, a10, w11*a11)));
                    sv[2*j+1] = fmaf(w00, b00, fmaf(w01, b01, fmaf(w10, b10, w11*b11)));
                }
            } else {
                const float* base = hrb + (size_t)(g*GP) * PLANE;
#pragma unroll
                for (int j = 0; j < GP; ++j) {
                    const float* p = base + (size_t)j * PLANE;
                    sv[j] = fmaf(w00, p[y0c*WW + x0c], fmaf(w01, p[y0c*WW + x1c],
                            fmaf(w10, p[y1c*WW + x0c], w11 * p[y1c*WW + x1c])));
                }
            }
            unsigned pk0 = pack2(sv[0], sv[1]), pk1 = pack2(sv[2], sv[3]);
            unsigned pk2 = pack2(sv[4], sv[5]), pk3 = pack2(sv[6], sv[7]);
            u32x4 pv = {pk0, pk1, pk2, pk3};
            if (tap < 8)
                *reinterpret_cast<u32x4*>((char*)samp0 + swz(px, tap*16)) = pv;
            else
                *reinterpret_cast<u32x4*>((char*)samp1 + px*16) = pv;
        }
        LGKM0_BAR();
        __builtin_amdgcn_s_setprio(1);
        MFMA_G();
        __builtin_amdgcn_s_setprio(0);
        RAW_BAR();
    }

#pragma unroll
    for (int mf = 0; mf < 2; ++mf)
#pragma unroll
        for (int r = 0; r < 4; ++r) {
            int oc = ocg4*32 + mf*16 + l4*4 + r;
            float bd = bias_lds[oc];
#pragma unroll
            for (int nf = 0; nf < 2; ++nf) {
                int px = pxg*32 + nf*16 + l15;
                outp[((size_t)(b*CC + oc)) * PLANE + h*WW + px] = acc[mf][nf][r] + bd;
            }
        }
#undef ISSUE_WGT
#undef WRITE_WGT
#undef ISSUE_PLANES
#undef STAGE_DIRECT
#undef MFMA_G
}

extern "C" void kernel_launch(void* const* d_in, const int* in_sizes, int n_in,
                              void* d_out, int out_size, void* d_ws, size_t ws_size,
                              hipStream_t stream)
{
    const float* lr    = (const float*)d_in[0];
    const float* hr    = (const float*)d_in[1];
    const float* w_off = (const float*)d_in[2];
    const float* b_off = (const float*)d_in[3];
    const float* w_def = (const float*)d_in[4];
    const float* b_def = (const float*)d_in[5];
    float* outp = (float*)d_out;

    const size_t wpad_b = (size_t)CC * NG * KSG * 2 + 256;      // 294912 + pad
    const size_t hrbf_b = (size_t)4 * NG * PLANE * GP * 2;      // 9437184
    const size_t lrbf_b = hrbf_b;
    const size_t woff_b = (size_t)32 * 32 * KSG * 2 + 256;      // 147456 + pad
    const size_t offw_b = (size_t)4 * 18 * PLANE * 4;           // 2654208

    unsigned short* wpad = (unsigned short*)d_ws;
    unsigned short* hrbf = (unsigned short*)((char*)d_ws + wpad_b);
    unsigned short* lrbf = (unsigned short*)((char*)d_ws + wpad_b + hrbf_b);
    unsigned short* wop  = (unsigned short*)((char*)d_ws + wpad_b + hrbf_b + lrbf_b);
    float*          offw = (float*)((char*)d_ws + wpad_b + hrbf_b + lrbf_b + woff_b);

    const bool full     = ws_size >= wpad_b + hrbf_b + lrbf_b + woff_b + offw_b;
    const bool use_hrbf = ws_size >= wpad_b + hrbf_b + lrbf_b;  // pc2 clamp may read into lrbf

    if (full) {
        prep_kernel<<<5472, 256, 0, stream>>>(hr, lr, w_def, w_off,
                                              hrbf, lrbf, wpad, wop);
        offset_mfma_kernel<<<4*HH, 768, 0, stream>>>(lrbf, hrbf, wop, b_off, offw);
        deform3_kernel<<<4*HH*2, 384, 0, stream>>>(hrbf, wpad, b_def, offw, outp);
    } else {
        wcvt_kernel<<<(CC*NG*KSG + 255)/256, 256, 0, stream>>>(w_def, wpad);
        if (use_hrbf)
            cvt8_kernel<<<(4*NG*PLANE)/256, 256, 0, stream>>>(hr, hrbf);
        offset_conv_kernel<<<4*36*NGRP, 256, 0, stream>>>(lr, hr, w_off, outp);
        if (use_hrbf)
            deform2_kernel<true, false><<<4*HH, 768, 0, stream>>>(
                hr, hrbf, b_off, wpad, b_def, offw, outp);
        else
            deform2_kernel<false, false><<<4*HH, 768, 0, stream>>>(
                hr, hrbf, b_off, wpad, b_def, offw, outp);
    }
}

// Round 19
// 84.784 us; speedup vs baseline: 1.6670x; 1.6670x over previous
//
#include <hip/hip_runtime.h>
#include <hip/hip_bf16.h>

#define HH 96
#define WW 96
#define CC 128
#define C2 256
#define PLANE (HH*WW)          // 9216
#define NGRP 6                 // fallback offset-conv channel groups
#define GP 8                   // ic per group
#define NG 16                  // hr groups
#define KSG 72                 // k-slots per group (9 taps * 8 ic)
#define ROWS 13                // fallback deform staged rows per plane window
#define NPCHK (ROWS*WW)        // 1248 16B plane chunks per group
#define PCHK_PAD 1280          // padded chunk count (uniform 2 loads/thread)
#define HPX 48                 // deform3 half-row pixels

typedef __attribute__((ext_vector_type(8))) short bf16x8;
typedef __attribute__((ext_vector_type(4))) float f32x4;
typedef __attribute__((ext_vector_type(4))) unsigned int u32x4;

__device__ __forceinline__ int swz(int row, int byte_in_row) {
    return row * 128 + (byte_in_row ^ ((row & 7) << 4));
}

__device__ __forceinline__ void gload_lds16(const void* g, void* l) {
    __builtin_amdgcn_global_load_lds(
        (const __attribute__((address_space(1))) char*)g,
        (__attribute__((address_space(3))) char*)l, 16, 0, 0);
}

__device__ __forceinline__ unsigned pack2(float a, float b) {
    return (unsigned)__bfloat16_as_ushort(__float2bfloat16(a)) |
           ((unsigned)__bfloat16_as_ushort(__float2bfloat16(b)) << 16);
}

#define MFMA16(A,B,C) __builtin_amdgcn_mfma_f32_16x16x32_bf16((A),(B),(C),0,0,0)

// counted waits + raw barriers (T3/T4); sched_barrier per rule #18
#define VMW4() { asm volatile("s_waitcnt vmcnt(4)" ::: "memory"); __builtin_amdgcn_sched_barrier(0); }
#define VMW0() { asm volatile("s_waitcnt vmcnt(0)" ::: "memory"); __builtin_amdgcn_sched_barrier(0); }
#define LGKM0_BAR() { asm volatile("s_waitcnt lgkmcnt(0)" ::: "memory"); \
    __builtin_amdgcn_sched_barrier(0); __builtin_amdgcn_s_barrier(); \
    __builtin_amdgcn_sched_barrier(0); }
#define RAW_BAR() { __builtin_amdgcn_sched_barrier(0); __builtin_amdgcn_s_barrier(); \
    __builtin_amdgcn_sched_barrier(0); }

// ------------- fused prep: hr->hrbf, lr->lrbf, w_def->wpad, w_off->wop -------------
__global__ __launch_bounds__(256) void prep_kernel(
    const float* __restrict__ hr, const float* __restrict__ lr,
    const float* __restrict__ w_def, const float* __restrict__ w_off,
    unsigned short* __restrict__ hrbf, unsigned short* __restrict__ lrbf,
    unsigned short* __restrict__ wpad, unsigned short* __restrict__ wop)
{
    const int bid = blockIdx.x;
    const int tid = threadIdx.x;
    if (bid < 4608) {                       // cvt8 for hr (0..2303) / lr (2304..4607)
        const bool is_hr = bid < 2304;
        const float* src0 = is_hr ? hr : lr;
        unsigned short* o = is_hr ? hrbf : lrbf;
        int idx = (is_hr ? bid : bid - 2304) * 256 + tid;
        int hw = idx % PLANE;
        int t  = idx / PLANE;
        int g  = t & 15;
        int b  = t >> 4;
        const float* src = src0 + ((size_t)(b * CC + g * GP)) * PLANE + hw;
        unsigned pk[4];
#pragma unroll
        for (int j = 0; j < 4; ++j)
            pk[j] = pack2(src[(size_t)(2*j) * PLANE], src[(size_t)(2*j+1) * PLANE]);
        u32x4 v = {pk[0], pk[1], pk[2], pk[3]};
        *reinterpret_cast<u32x4*>(o + (size_t)idx * 8) = v;
    } else if (bid < 5184) {                // wcvt: 147456 elems
        int i = (bid - 4608) * 256 + tid;
        int oc = i / (NG * KSG);
        int r  = i - oc * (NG * KSG);
        int g  = r / KSG;
        int s  = r - g * KSG;
        int tap = s >> 3;
        int icoff = s & 7;
        wpad[i] = __bfloat16_as_ushort(__float2bfloat16(
            w_def[(size_t)(oc * CC + g * GP + icoff) * 9 + tap]));
    } else {                                // woffcvt: 73728 elems
        int i = (bid - 5184) * 256 + tid;
        int oc = i / (32 * KSG);
        int r  = i - oc * (32 * KSG);
        int g  = r / KSG;
        int s  = r - g * KSG;
        int tap = s >> 3;
        int icoff = s & 7;
        int c = g * 8 + icoff;
        float v = (oc < 18) ? w_off[(size_t)(oc * C2 + c) * 9 + tap] : 0.f;
        wop[i] = __bfloat16_as_ushort(__float2bfloat16(v));
    }
}

// ------------- standalone converts (fallback paths only) ---------------------------
__global__ __launch_bounds__(256) void wcvt_kernel(const float* __restrict__ w,
                                                   unsigned short* __restrict__ o)
{
    int i = blockIdx.x * 256 + threadIdx.x;
    if (i < CC * NG * KSG) {
        int oc = i / (NG * KSG);
        int r  = i - oc * (NG * KSG);
        int g  = r / KSG;
        int s  = r - g * KSG;
        int tap = s >> 3;
        int icoff = s & 7;
        o[i] = __bfloat16_as_ushort(__float2bfloat16(
            w[(size_t)(oc * CC + g * GP + icoff) * 9 + tap]));
    }
}

__global__ __launch_bounds__(256) void cvt8_kernel(const float* __restrict__ src0,
                                                   unsigned short* __restrict__ o)
{
    int idx = blockIdx.x * 256 + threadIdx.x;
    int hw = idx % PLANE;
    int t  = idx / PLANE;
    int g  = t & 15;
    int b  = t >> 4;
    const float* src = src0 + ((size_t)(b * CC + g * GP)) * PLANE + hw;
    unsigned pk[4];
#pragma unroll
    for (int j = 0; j < 4; ++j)
        pk[j] = pack2(src[(size_t)(2*j) * PLANE], src[(size_t)(2*j+1) * PLANE]);
    u32x4 v = {pk[0], pk[1], pk[2], pk[3]};
    *reinterpret_cast<u32x4*>(o + (size_t)idx * 8) = v;
}

// ------------- Kernel 1 (fallback): fp32 offset conv, partials into d_out ----------
__global__ __launch_bounds__(256) void offset_conv_kernel(
    const float* __restrict__ lr, const float* __restrict__ hr,
    const float* __restrict__ w_off, float* __restrict__ outp)
{
    __shared__ float tile[2][324];
    const int bid = blockIdx.x;
    const int q   = bid % NGRP;
    const int t   = bid / NGRP;
    const int b   = t / 36;
    const int rr  = t % 36;
    const int h0  = (rr / 6) * 16;
    const int w0  = (rr % 6) * 16;
    const int tid = threadIdx.x;
    const int py  = tid >> 4;
    const int px  = tid & 15;

    const int c0 = (C2 * q) / NGRP, c1 = (C2 * (q + 1)) / NGRP;
    const float* srcp = (q < 3) ? lr : hr;
    const int cofs = (q < 3) ? 0 : CC;

    int gy0 = h0 - 1 + tid / 18, gx0 = w0 - 1 + tid % 18;
    bool ok0 = (unsigned)gy0 < (unsigned)HH && (unsigned)gx0 < (unsigned)WW;
    int off0 = gy0 * WW + gx0;
    int j1 = tid + 256;
    int gy1 = h0 - 1 + j1 / 18, gx1 = w0 - 1 + j1 % 18;
    bool ok1 = (j1 < 324) && (unsigned)gy1 < (unsigned)HH && (unsigned)gx1 < (unsigned)WW;
    int off1 = gy1 * WW + gx1;

    float acc[18];
#pragma unroll
    for (int oc = 0; oc < 18; ++oc) acc[oc] = 0.f;

    const float* pl = srcp + (size_t)(b * CC + c0 - cofs) * PLANE;
    float p0 = ok0 ? pl[off0] : 0.f;
    float p1 = ok1 ? pl[off1] : 0.f;

    for (int c = c0; c < c1; ++c) {
        float* tb = tile[c & 1];
        tb[tid] = p0;
        if (j1 < 324) tb[j1] = p1;
        __syncthreads();
        if (c + 1 < c1) {
            const float* pn = srcp + (size_t)(b * CC + c + 1 - cofs) * PLANE;
            p0 = ok0 ? pn[off0] : 0.f;
            p1 = ok1 ? pn[off1] : 0.f;
        }
        float tv[9];
#pragma unroll
        for (int ky = 0; ky < 3; ++ky)
#pragma unroll
            for (int kx = 0; kx < 3; ++kx)
                tv[ky*3+kx] = tb[(py+ky)*18 + px + kx];
#pragma unroll
        for (int oc = 0; oc < 18; ++oc) {
            const float* wp = w_off + (size_t)(oc * C2 + c) * 9;
#pragma unroll
            for (int tap = 0; tap < 9; ++tap)
                acc[oc] = fmaf(wp[tap], tv[tap], acc[oc]);
        }
    }
#pragma unroll
    for (int oc = 0; oc < 18; ++oc)
        outp[((size_t)(b*CC + q*18 + oc)) * PLANE + (h0+py)*WW + (w0+px)] = acc[oc];
}

// ------------- Kernel 1': offset conv, 2 c-groups per iteration --------------------
__global__ __launch_bounds__(768, 6) void offset_mfma_kernel(
    const unsigned short* __restrict__ lrbf, const unsigned short* __restrict__ hrbf,
    const unsigned short* __restrict__ wop, const float* __restrict__ b_off,
    float* __restrict__ offw)
{
    __shared__ __align__(16) unsigned short planes[2][2][3*WW*8];  // dbuf x grp: 18.4KB
    __shared__ __align__(16) unsigned short wgt0[2][32*64];        // 8KB swz
    __shared__ __align__(16) unsigned short wgt1[2][32*8];         // 1KB
    __shared__ __align__(16) unsigned short samp0[2][WW*64];       // 24.6KB swz
    __shared__ __align__(16) unsigned short samp1[2][WW*8];        // 3KB

    const int rawb = blockIdx.x;
    const int bid  = (rawb & 7) * 48 + (rawb >> 3);   // XCD swizzle
    const int b    = bid / HH;
    const int h    = bid % HH;
    const int tid  = threadIdx.x;

    const int pri = tid / 96, ppx = tid - (tid / 96) * 96;
    const int prow = min(max(h - 1 + pri, 0), HH - 1);

    const int woc = tid / 9, wsl = tid % 9;
    float4 wv0, wv1;

#define ISSUE_P2(PAIR, PB) { \
    if (tid < 288) { \
        int gA_ = 2*(PAIR), gB_ = gA_ + 1; \
        const unsigned short* bA_ = (gA_ < 16 ? lrbf : hrbf); \
        const unsigned short* bB_ = (gB_ < 16 ? lrbf : hrbf); \
        gload_lds16(bA_ + ((size_t)(b*16 + (gA_ & 15)) * PLANE + prow*WW + ppx) * 8, \
                    (char*)planes[PB][0] + tid*16); \
        gload_lds16(bB_ + ((size_t)(b*16 + (gB_ & 15)) * PLANE + prow*WW + ppx) * 8, \
                    (char*)planes[PB][1] + tid*16); \
    } }
#define ISSUE_W2(PAIR) { \
    if (tid < 288) { \
        wv0 = *reinterpret_cast<const float4*>(wop + ((size_t)(woc*32 + 2*(PAIR)    ))*KSG + wsl*8); \
        wv1 = *reinterpret_cast<const float4*>(wop + ((size_t)(woc*32 + 2*(PAIR) + 1))*KSG + wsl*8); \
    } }
#define WRITE_W2() { \
    if (tid < 288) { \
        if (wsl < 8) { \
            *reinterpret_cast<float4*>((char*)wgt0[0] + swz(woc, wsl*16)) = wv0; \
            *reinterpret_cast<float4*>((char*)wgt0[1] + swz(woc, wsl*16)) = wv1; \
        } else { \
            *reinterpret_cast<float4*>((char*)wgt1[0] + woc*16) = wv0; \
            *reinterpret_cast<float4*>((char*)wgt1[1] + woc*16) = wv1; \
        } \
    } }

    const int tap1 = tid / WW, px1 = tid - (tid / WW) * WW;   // taps 0..7
    const int ky1 = tap1 / 3 - 1, kx1 = tap1 % 3 - 1;
    const int row1 = h + ky1, x1 = px1 + kx1;
    const bool ok1 = (unsigned)row1 < (unsigned)HH && (unsigned)x1 < (unsigned)WW;
    const int ro1 = ((ky1+1)*WW + x1) * 16;
    const int wr1 = px1*128 + ((tap1*16) ^ ((px1 & 7) << 4));
    const int x2 = tid + 1;                                    // item2: tap 8
    const bool ok2 = (tid < 96) && (h + 1 < HH) && (x2 < WW);
    const int ro2 = (2*WW + x2) * 16;
    const int wr2 = tid * 16;

    const int lane = tid & 63;
    const int wid  = tid >> 6;
    const int ocg  = wid / 6;          // 0..1
    const int pxg  = wid - ocg * 6;    // 0..5
    const int l15  = lane & 15;
    const int l4   = lane >> 4;
    const int rowA = ocg*16 + l15;
    const int rowB = pxg*16 + l15;
    const bf16x8 zf = {};

    f32x4 acc = (f32x4){0.f, 0.f, 0.f, 0.f};

#define MFMA_O2() { \
    _Pragma("unroll") \
    for (int q_ = 0; q_ < 2; ++q_) { \
        bf16x8 a0_ = *reinterpret_cast<const bf16x8*>((char*)wgt0[q_] + swz(rowA, l4*16)); \
        bf16x8 a1_ = *reinterpret_cast<const bf16x8*>((char*)wgt0[q_] + swz(rowA, 64 + l4*16)); \
        bf16x8 a2_ = *reinterpret_cast<const bf16x8*>((char*)wgt1[q_] + rowA*16); \
        if (l4) a2_ = zf; \
        bf16x8 b0_ = *reinterpret_cast<const bf16x8*>((char*)samp0[q_] + swz(rowB, l4*16)); \
        bf16x8 b1_ = *reinterpret_cast<const bf16x8*>((char*)samp0[q_] + swz(rowB, 64 + l4*16)); \
        bf16x8 b2_ = *reinterpret_cast<const bf16x8*>((char*)samp1[q_] + rowB*16); \
        acc = MFMA16(a0_, b0_, acc); \
        acc = MFMA16(a1_, b1_, acc); \
        acc = MFMA16(a2_, b2_, acc); \
    } }

    ISSUE_W2(0);
    ISSUE_P2(0, 0);
    __syncthreads();

    for (int p2 = 0; p2 < 16; ++p2) {
        const int sb = p2 & 1;
        WRITE_W2();
        if (p2 < 15) {
            ISSUE_W2(p2 + 1);
            ISSUE_P2(p2 + 1, sb ^ 1);
            VMW4();
        } else {
            VMW0();
        }
        RAW_BAR();
        {
            u32x4 vA = {0u, 0u, 0u, 0u}, vB = {0u, 0u, 0u, 0u};
            if (ok1) {
                vA = *reinterpret_cast<const u32x4*>((const char*)planes[sb][0] + ro1);
                vB = *reinterpret_cast<const u32x4*>((const char*)planes[sb][1] + ro1);
            }
            *reinterpret_cast<u32x4*>((char*)samp0[0] + wr1) = vA;
            *reinterpret_cast<u32x4*>((char*)samp0[1] + wr1) = vB;
            if (tid < 96) {
                u32x4 wA = {0u, 0u, 0u, 0u}, wB = {0u, 0u, 0u, 0u};
                if (ok2) {
                    wA = *reinterpret_cast<const u32x4*>((const char*)planes[sb][0] + ro2);
                    wB = *reinterpret_cast<const u32x4*>((const char*)planes[sb][1] + ro2);
                }
                *reinterpret_cast<u32x4*>((char*)samp1[0] + wr2) = wA;
                *reinterpret_cast<u32x4*>((char*)samp1[1] + wr2) = wB;
            }
        }
        LGKM0_BAR();
        __builtin_amdgcn_s_setprio(1);
        MFMA_O2();
        __builtin_amdgcn_s_setprio(0);
        RAW_BAR();
    }

#pragma unroll
    for (int r = 0; r < 4; ++r) {
        int oc = ocg*16 + l4*4 + r;
        if (oc < 18)
            offw[((size_t)(b*18 + oc)) * PLANE + h*WW + pxg*16 + l15] = acc[r] + b_off[oc];
    }
#undef ISSUE_P2
#undef ISSUE_W2
#undef WRITE_W2
#undef MFMA_O2
}

// ------------- Kernel 2': deformable conv, direct-global gather, half-row blocks ---
// grid: 768 blocks (XCD-swizzled), 384 threads (6 waves: 2 ocg x 3 pxg)
__global__ __launch_bounds__(384, 6) void deform3_kernel(
    const unsigned short* __restrict__ hrbf, const unsigned short* __restrict__ wpad,
    const float* __restrict__ b_def, const float* __restrict__ offw,
    float* __restrict__ outp)
{
    __shared__ __align__(16) unsigned short wgt0[CC*64];     // 16KB swz
    __shared__ __align__(16) unsigned short wgt1[CC*8];      // 2KB
    __shared__ __align__(16) unsigned short samp0[HPX*64];   // 6KB swz
    __shared__ __align__(16) unsigned short samp1[HPX*8];    // 768B
    __shared__ __align__(16) float4 gw4[9*HPX];              // 6.75KB masked weights
    __shared__ __align__(8)  short4 gyo[9*HPX];              // 3.4KB clamped y0,y1,x0,x1
    __shared__ float bias_lds[CC];

    const int rawb = blockIdx.x;
    const int bid  = (rawb & 7) * 96 + (rawb >> 3);   // XCD swizzle (768%8==0)
    const int b    = bid / 192;
    const int t2   = bid % 192;
    const int h    = t2 >> 1;
    const int half = t2 & 1;
    const int px0  = half * HPX;
    const int tid  = threadIdx.x;

    // wgt staging: 1152 chunks over 384 threads = 3 each
    float4 wv0, wv1, wv2;
    const int c0 = tid,        w0oc = c0 / 9, w0s = c0 % 9;
    const int c1 = tid + 384,  w1oc = c1 / 9, w1s = c1 % 9;
    const int c2 = tid + 768,  w2oc = c2 / 9, w2s = c2 % 9;

#define ISSUE_WGT(G) { \
    wv0 = *reinterpret_cast<const float4*>(wpad + ((size_t)(w0oc*NG + (G))*KSG + w0s*8)); \
    wv1 = *reinterpret_cast<const float4*>(wpad + ((size_t)(w1oc*NG + (G))*KSG + w1s*8)); \
    wv2 = *reinterpret_cast<const float4*>(wpad + ((size_t)(w2oc*NG + (G))*KSG + w2s*8)); }
#define WRITE_WGT() { \
    if (w0s < 8) *reinterpret_cast<float4*>((char*)wgt0 + swz(w0oc, w0s*16)) = wv0; \
    else         *reinterpret_cast<float4*>((char*)wgt1 + w0oc*16) = wv0; \
    if (w1s < 8) *reinterpret_cast<float4*>((char*)wgt0 + swz(w1oc, w1s*16)) = wv1; \
    else         *reinterpret_cast<float4*>((char*)wgt1 + w1oc*16) = wv1; \
    if (w2s < 8) *reinterpret_cast<float4*>((char*)wgt0 + swz(w2oc, w2s*16)) = wv2; \
    else         *reinterpret_cast<float4*>((char*)wgt1 + w2oc*16) = wv2; }

    // ---- prologue: issue wgt(0), compute full geometry into LDS once ----
    ISSUE_WGT(0);

    for (int it = tid; it < 9 * HPX; it += 384) {
        int tap = it / HPX;
        int px  = it - tap * HPX;
        int gx  = px0 + px;
        int hw  = h * WW + gx;
        float offy = offw[((size_t)(b*18 + 2*tap    )) * PLANE + hw];
        float offx = offw[((size_t)(b*18 + 2*tap + 1)) * PLANE + hw];
        float sy = (float)h  + (float)(tap/3 - 1) + offy;
        float sx = (float)gx + (float)(tap%3 - 1) + offx;
        float y0f = floorf(sy), x0f = floorf(sx);
        float dy = sy - y0f, dx = sx - x0f;
        int y0 = (int)y0f, x0 = (int)x0f;
        bool y0v = (unsigned)y0       < (unsigned)HH;
        bool y1v = (unsigned)(y0 + 1) < (unsigned)HH;
        bool x0v = (unsigned)x0       < (unsigned)WW;
        bool x1v = (unsigned)(x0 + 1) < (unsigned)WW;
        float ody = 1.f - dy, odx = 1.f - dx;
        float4 wv;
        wv.x = (y0v && x0v) ? ody*odx : 0.f;
        wv.y = (y0v && x1v) ? ody*dx  : 0.f;
        wv.z = (y1v && x0v) ? dy*odx  : 0.f;
        wv.w = (y1v && x1v) ? dy*dx   : 0.f;
        short4 o4;
        o4.x = (short)min(max(y0,     0), HH-1);
        o4.y = (short)min(max(y0 + 1, 0), HH-1);
        o4.z = (short)min(max(x0,     0), WW-1);
        o4.w = (short)min(max(x0 + 1, 0), WW-1);
        gw4[it] = wv;
        gyo[it] = o4;
    }
    if (tid < CC) bias_lds[tid] = b_def[tid];
    __syncthreads();    // geometry visible; wgt(0) drained

    const int lane = tid & 63;
    const int wid  = tid >> 6;        // 0..5
    const int ocg  = wid / 3;         // 0..1 (64 oc each)
    const int pxg  = wid - ocg * 3;   // 0..2 (16 px each)
    const int l15  = lane & 15;
    const int l4   = lane >> 4;

    f32x4 acc[4];
#pragma unroll
    for (int mf = 0; mf < 4; ++mf) acc[mf] = (f32x4){0.f, 0.f, 0.f, 0.f};

    const int rowB = pxg*16 + l15;    // 0..47
    const bf16x8 zf = {};

#define MFMA_G() { \
    _Pragma("unroll") \
    for (int ks = 0; ks < 2; ++ks) { \
        int kb = ks*64 + l4*16; \
        bf16x8 bb = *reinterpret_cast<const bf16x8*>((char*)samp0 + swz(rowB, kb)); \
        _Pragma("unroll") \
        for (int mf = 0; mf < 4; ++mf) { \
            bf16x8 aa = *reinterpret_cast<const bf16x8*>((char*)wgt0 + swz(ocg*64 + mf*16 + l15, kb)); \
            acc[mf] = MFMA16(aa, bb, acc[mf]); \
        } \
    } \
    { \
        bf16x8 bb = *reinterpret_cast<const bf16x8*>((char*)samp1 + rowB*16); \
        _Pragma("unroll") \
        for (int mf = 0; mf < 4; ++mf) { \
            bf16x8 aa = *reinterpret_cast<const bf16x8*>((char*)wgt1 + (ocg*64 + mf*16 + l15)*16); \
            if (l4) aa = zf; \
            acc[mf] = MFMA16(aa, bb, acc[mf]); \
        } \
    } }

    const unsigned short* gb = hrbf + (size_t)(b * NG) * PLANE * 8;

    // ---- main loop: direct-global gather BUILD; 2 raw barriers per group ----
    for (int g = 0; g < NG; ++g) {
        WRITE_WGT();                       // wgt(g) regs -> LDS (compiler-counted wait)
        if (g < NG - 1) ISSUE_WGT(g + 1);  // 3 reg loads fly across barriers
        const unsigned short* gpl = gb + (size_t)g * PLANE * 8;
        for (int it = tid; it < 9 * HPX; it += 384) {
            float4 w4 = gw4[it];
            short4 o4 = gyo[it];
            int ra = (int)o4.x * WW, rb = (int)o4.y * WW;
            u32x4 q00 = *reinterpret_cast<const u32x4*>(gpl + (size_t)(ra + o4.z) * 8);
            u32x4 q01 = *reinterpret_cast<const u32x4*>(gpl + (size_t)(ra + o4.w) * 8);
            u32x4 q10 = *reinterpret_cast<const u32x4*>(gpl + (size_t)(rb + o4.z) * 8);
            u32x4 q11 = *reinterpret_cast<const u32x4*>(gpl + (size_t)(rb + o4.w) * 8);
            float sv[GP];
#pragma unroll
            for (int j = 0; j < 4; ++j) {
                float a00 = __uint_as_float(q00[j] << 16), b00 = __uint_as_float(q00[j] & 0xffff0000u);
                float a01 = __uint_as_float(q01[j] << 16), b01 = __uint_as_float(q01[j] & 0xffff0000u);
                float a10 = __uint_as_float(q10[j] << 16), b10 = __uint_as_float(q10[j] & 0xffff0000u);
                float a11 = __uint_as_float(q11[j] << 16), b11 = __uint_as_float(q11[j] & 0xffff0000u);
                sv[2*j]   = fmaf(w4.x, a00, fmaf(w4.y, a01, fmaf(w4.z, a10, w4.w*a11)));
                sv[2*j+1] = fmaf(w4.x, b00, fmaf(w4.y, b01, fmaf(w4.z, b10, w4.w*b11)));
            }
            unsigned pk0 = pack2(sv[0], sv[1]), pk1 = pack2(sv[2], sv[3]);
            unsigned pk2 = pack2(sv[4], sv[5]), pk3 = pack2(sv[6], sv[7]);
            u32x4 pv = {pk0, pk1, pk2, pk3};
            int tap = it / HPX;
            int px  = it - tap * HPX;
            if (tap < 8)
                *reinterpret_cast<u32x4*>((char*)samp0 + swz(px, tap*16)) = pv;
            else
                *reinterpret_cast<u32x4*>((char*)samp1 + px*16) = pv;
        }
        LGKM0_BAR();     // samp(g)+wgt(g) visible to all waves
        __builtin_amdgcn_s_setprio(1);
        MFMA_G();        // consumes wgt(g), samp(g)
        __builtin_amdgcn_s_setprio(0);
        RAW_BAR();       // all waves' MFMA reads done before next overwrite
    }

    // ---- epilogue ----
#pragma unroll
    for (int mf = 0; mf < 4; ++mf)
#pragma unroll
        for (int r = 0; r < 4; ++r) {
            int oc = ocg*64 + mf*16 + l4*4 + r;
            float bd = bias_lds[oc];
            outp[((size_t)(b*CC + oc)) * PLANE + h*WW + px0 + pxg*16 + l15] = acc[mf][r] + bd;
        }
#undef ISSUE_WGT
#undef WRITE_WGT
#undef MFMA_G
}

// ------------- Kernel 2 (fallback): deformable conv with LDS planes ----------------
template<bool HRBF, bool OFFWS>
__global__ __launch_bounds__(768, 6) void deform2_kernel(
    const float* __restrict__ hr, const unsigned short* __restrict__ hrbf,
    const float* __restrict__ b_off, const unsigned short* __restrict__ wpad,
    const float* __restrict__ b_def, const float* __restrict__ offw,
    float* __restrict__ outp)
{
    __shared__ __align__(16) unsigned short planes[2][PCHK_PAD*8];  // 2x20480B
    __shared__ __align__(16) unsigned short wgt0[CC*64];            // 16KB swz
    __shared__ __align__(16) unsigned short wgt1[CC*8];             // 2KB
    __shared__ __align__(16) unsigned short samp0[WW*64];           // 12KB swz
    __shared__ __align__(16) unsigned short samp1[WW*8];            // 1.5KB
    __shared__ __align__(8)  float2 geom[9*97];                     // 6984B
    __shared__ float bias_lds[CC];

    const int rawb = blockIdx.x;
    const int bid  = (rawb & 7) * 48 + (rawb >> 3);
    const int b    = bid / HH;
    const int h    = bid % HH;
    const int tid  = threadIdx.x;
    const int r0   = min(max(h - 6, 0), HH - ROWS);

    const float* hrb = hr + (size_t)b * CC * PLANE;

    float4 wv0, wv1;
    const int wc0oc = tid / 9, wc0s = tid % 9;
    const int wt2   = (tid < 384) ? tid + 768 : tid;
    const int wc1oc = wt2 / 9, wc1s = wt2 % 9;
    const int pc2   = (tid < 512) ? tid + 768 : tid;
    const int pcs   = min(pc2, NPCHK - 1);

#define ISSUE_WGT(G) { \
    wv0 = *reinterpret_cast<const float4*>(wpad + ((size_t)(wc0oc*NG + (G))*KSG + wc0s*8)); \
    wv1 = *reinterpret_cast<const float4*>(wpad + ((size_t)(wc1oc*NG + (G))*KSG + wc1s*8)); }
#define WRITE_WGT() { \
    if (wc0s < 8) *reinterpret_cast<float4*>((char*)wgt0 + swz(wc0oc, wc0s*16)) = wv0; \
    else          *reinterpret_cast<float4*>((char*)wgt1 + wc0oc*16) = wv0; \
    if (tid < 384) { \
        if (wc1s < 8) *reinterpret_cast<float4*>((char*)wgt0 + swz(wc1oc, wc1s*16)) = wv1; \
        else          *reinterpret_cast<float4*>((char*)wgt1 + wc1oc*16) = wv1; \
    } }

#define ISSUE_PLANES(G, PB) { \
    const unsigned short* src_ = hrbf + ((size_t)(b*NG + (G))*PLANE + r0*WW)*8; \
    gload_lds16(src_ + (size_t)tid*8, (char*)planes[PB] + tid*16); \
    gload_lds16(src_ + (size_t)pcs*8, (char*)planes[PB] + pc2*16); }

#define STAGE_DIRECT(G, PB) { \
    for (int p = tid; p < NPCHK; p += 768) { \
        int r_ = p / WW, x_ = p - (p / WW) * WW; \
        const float* s_ = hrb + (size_t)((G)*GP) * PLANE + (r0 + r_)*WW + x_; \
        unsigned pk_[4]; \
        _Pragma("unroll") \
        for (int j = 0; j < 4; ++j) \
            pk_[j] = pack2(s_[(size_t)(2*j)*PLANE], s_[(size_t)(2*j+1)*PLANE]); \
        u32x4 v_ = {pk_[0], pk_[1], pk_[2], pk_[3]}; \
        *reinterpret_cast<u32x4*>((char*)planes[PB] + p*16) = v_; \
    } }

    if (HRBF) ISSUE_PLANES(0, 0);
    ISSUE_WGT(0);

    for (int t = tid; t < 9 * WW; t += 768) {
        int tap = t / WW;
        int px  = t - tap * WW;
        int hw  = h * WW + px;
        float offy, offx;
        if (OFFWS) {
            offy = offw[((size_t)(b*18 + 2*tap    )) * PLANE + hw];
            offx = offw[((size_t)(b*18 + 2*tap + 1)) * PLANE + hw];
        } else {
            offy = b_off[2*tap]; offx = b_off[2*tap + 1];
#pragma unroll
            for (int q = 0; q < NGRP; ++q) {
                offy += outp[((size_t)(b*CC + q*18 + 2*tap    )) * PLANE + hw];
                offx += outp[((size_t)(b*CC + q*18 + 2*tap + 1)) * PLANE + hw];
            }
        }
        geom[tap*97 + px] = make_float2((float)h  + (float)(tap/3 - 1) + offy,
                                        (float)px + (float)(tap%3 - 1) + offx);
    }
    if (tid < CC) bias_lds[tid] = b_def[tid];
    if (!HRBF) STAGE_DIRECT(0, 0);
    __syncthreads();

    const int lane = tid & 63;
    const int wid  = tid >> 6;
    const int ocg4 = wid / 3;
    const int pxg  = wid - ocg4 * 3;
    const int l15  = lane & 15;
    const int l4   = lane >> 4;

    f32x4 acc[2][2];
#pragma unroll
    for (int mf = 0; mf < 2; ++mf)
#pragma unroll
        for (int nf = 0; nf < 2; ++nf)
            acc[mf][nf] = (f32x4){0.f, 0.f, 0.f, 0.f};

    const int rowA0 = ocg4*32 + l15, rowA1 = rowA0 + 16;
    const int rowB0 = pxg*32 + l15,  rowB1 = rowB0 + 16;
    const bf16x8 zf = {};

#define MFMA_G() { \
    bf16x8 a00_ = *reinterpret_cast<const bf16x8*>((char*)wgt0 + swz(rowA0, l4*16)); \
    bf16x8 a10_ = *reinterpret_cast<const bf16x8*>((char*)wgt0 + swz(rowA1, l4*16)); \
    bf16x8 a01_ = *reinterpret_cast<const bf16x8*>((char*)wgt0 + swz(rowA0, 64 + l4*16)); \
    bf16x8 a11_ = *reinterpret_cast<const bf16x8*>((char*)wgt0 + swz(rowA1, 64 + l4*16)); \
    bf16x8 a02_ = *reinterpret_cast<const bf16x8*>((char*)wgt1 + rowA0*16); \
    bf16x8 a12_ = *reinterpret_cast<const bf16x8*>((char*)wgt1 + rowA1*16); \
    if (l4) { a02_ = zf; a12_ = zf; } \
    const char* s0_ = (const char*)samp0; \
    const char* s1_ = (const char*)samp1; \
    bf16x8 b00_ = *reinterpret_cast<const bf16x8*>(s0_ + swz(rowB0, l4*16)); \
    bf16x8 b10_ = *reinterpret_cast<const bf16x8*>(s0_ + swz(rowB1, l4*16)); \
    bf16x8 b01_ = *reinterpret_cast<const bf16x8*>(s0_ + swz(rowB0, 64 + l4*16)); \
    bf16x8 b11_ = *reinterpret_cast<const bf16x8*>(s0_ + swz(rowB1, 64 + l4*16)); \
    bf16x8 b02_ = *reinterpret_cast<const bf16x8*>(s1_ + rowB0*16); \
    bf16x8 b12_ = *reinterpret_cast<const bf16x8*>(s1_ + rowB1*16); \
    acc[0][0] = MFMA16(a00_, b00_, acc[0][0]); \
    acc[0][1] = MFMA16(a00_, b10_, acc[0][1]); \
    acc[1][0] = MFMA16(a10_, b00_, acc[1][0]); \
    acc[1][1] = MFMA16(a10_, b10_, acc[1][1]); \
    acc[0][0] = MFMA16(a01_, b01_, acc[0][0]); \
    acc[0][1] = MFMA16(a01_, b11_, acc[0][1]); \
    acc[1][0] = MFMA16(a11_, b01_, acc[1][0]); \
    acc[1][1] = MFMA16(a11_, b11_, acc[1][1]); \
    acc[0][0] = MFMA16(a02_, b02_, acc[0][0]); \
    acc[0][1] = MFMA16(a02_, b12_, acc[0][1]); \
    acc[1][0] = MFMA16(a12_, b02_, acc[1][0]); \
    acc[1][1] = MFMA16(a12_, b12_, acc[1][1]); }

    for (int g = 0; g < NG; ++g) {
        const int pb = g & 1;
        WRITE_WGT();
        if (g < NG - 1) {
            ISSUE_WGT(g + 1);
            if (HRBF) { ISSUE_PLANES(g + 1, pb ^ 1); }
            else      { STAGE_DIRECT(g + 1, pb ^ 1); }
            if (HRBF) { VMW4(); }
        } else {
            if (HRBF) { VMW0(); }
        }
        for (int it = tid; it < 9 * WW; it += 768) {
            int tap = it / WW;
            int px  = it - tap * WW;
            float2 s2 = geom[tap*97 + px];
            float sy = s2.x, sx = s2.y;
            float y0f = floorf(sy), x0f = floorf(sx);
            float dy = sy - y0f, dx = sx - x0f;
            int y0 = (int)y0f, x0 = (int)x0f;
            bool y0v = (unsigned)y0       < (unsigned)HH;
            bool y1v = (unsigned)(y0 + 1) < (unsigned)HH;
            bool x0v = (unsigned)x0       < (unsigned)WW;
            bool x1v = (unsigned)(x0 + 1) < (unsigned)WW;
            float ody = 1.f - dy, odx = 1.f - dx;
            float w00 = (y0v && x0v) ? ody*odx : 0.f;
            float w01 = (y0v && x1v) ? ody*dx  : 0.f;
            float w10 = (y1v && x0v) ? dy*odx  : 0.f;
            float w11 = (y1v && x1v) ? dy*dx   : 0.f;
            int y0c = min(max(y0, 0), HH-1), y1c = min(max(y0+1, 0), HH-1);
            int x0c = min(max(x0, 0), WW-1), x1c = min(max(x0+1, 0), WW-1);
            float sv[GP];
            bool ng = (y0v && (unsigned)(y0 - r0) >= (unsigned)ROWS) ||
                      (y1v && (unsigned)(y1c - r0) >= (unsigned)ROWS);
            if (__builtin_expect(!ng, 1)) {
                int ra = min(max(y0c - r0, 0), ROWS-1);
                int rb = min(max(y1c - r0, 0), ROWS-1);
                const char* pbase = (const char*)planes[pb];
                u32x4 q00 = *reinterpret_cast<const u32x4*>(pbase + (ra*WW + x0c)*16);
                u32x4 q01 = *reinterpret_cast<const u32x4*>(pbase + (ra*WW + x1c)*16);
                u32x4 q10 = *reinterpret_cast<const u32x4*>(pbase + (rb*WW + x0c)*16);
                u32x4 q11 = *reinterpret_cast<const u32x4*>(pbase + (rb*WW + x1c)*16);
#pragma unroll
                for (int j = 0; j < 4; ++j) {
                    float a00 = __uint_as_float(q00[j] << 16), b00 = __uint_as_float(q00[j] & 0xffff0000u);
                    float a01 = __uint_as_float(q01[j] << 16), b01 = __uint_as_float(q01[j] & 0xffff0000u);
                    float a10 = __uint_as_float(q10[j] << 16), b10 = __uint_as_float(q10[j] & 0xffff0000u);
                    float a11 = __uint_as_float(q11[j] << 16), b11 = __uint_as_float(q11[j] & 0xffff0000u);
                    sv[2*j]   = fmaf(w00, a00, fmaf(w01, a01, fmaf(w10, a10, w11*a11)));
                    sv[2*j+1] = fmaf(w00, b00, fmaf(w01, b01, fmaf(w10, b10, w11*b11)));
                }
            } else {
                const float* base = hrb + (size_t)(g*GP) * PLANE;
#pragma unroll
                for (int j = 0; j < GP; ++j) {
                    const float* p = base + (size_t)j * PLANE;
                    sv[j] = fmaf(w00, p[y0c*WW + x0c], fmaf(w01, p[y0c*WW + x1c],
                            fmaf(w10, p[y1c*WW + x0c], w11 * p[y1c*WW + x1c])));
                }
            }
            unsigned pk0 = pack2(sv[0], sv[1]), pk1 = pack2(sv[2], sv[3]);
            unsigned pk2 = pack2(sv[4], sv[5]), pk3 = pack2(sv[6], sv[7]);
            u32x4 pv = {pk0, pk1, pk2, pk3};
            if (tap < 8)
                *reinterpret_cast<u32x4*>((char*)samp0 + swz(px, tap*16)) = pv;
            else
                *reinterpret_cast<u32x4*>((char*)samp1 + px*16) = pv;
        }
        LGKM0_BAR();
        __builtin_amdgcn_s_setprio(1);
        MFMA_G();
        __builtin_amdgcn_s_setprio(0);
        RAW_BAR();
    }

#pragma unroll
    for (int mf = 0; mf < 2; ++mf)
#pragma unroll
        for (int r = 0; r < 4; ++r) {
            int oc = ocg4*32 + mf*16 + l4*4 + r;
            float bd = bias_lds[oc];
#pragma unroll
            for (int nf = 0; nf < 2; ++nf) {
                int px = pxg*32 + nf*16 + l15;
                outp[((size_t)(b*CC + oc)) * PLANE + h*WW + px] = acc[mf][nf][r] + bd;
            }
        }
#undef ISSUE_WGT
#undef WRITE_WGT
#undef ISSUE_PLANES
#undef STAGE_DIRECT
#undef MFMA_G
}

extern "C" void kernel_launch(void* const* d_in, const int* in_sizes, int n_in,
                              void* d_out, int out_size, void* d_ws, size_t ws_size,
                              hipStream_t stream)
{
    const float* lr    = (const float*)d_in[0];
    const float* hr    = (const float*)d_in[1];
    const float* w_off = (const float*)d_in[2];
    const float* b_off = (const float*)d_in[3];
    const float* w_def = (const float*)d_in[4];
    const float* b_def = (const float*)d_in[5];
    float* outp = (float*)d_out;

    const size_t wpad_b = (size_t)CC * NG * KSG * 2 + 256;      // 294912 + pad
    const size_t hrbf_b = (size_t)4 * NG * PLANE * GP * 2;      // 9437184
    const size_t lrbf_b = hrbf_b;
    const size_t woff_b = (size_t)32 * 32 * KSG * 2 + 256;      // 147456 + pad
    const size_t offw_b = (size_t)4 * 18 * PLANE * 4;           // 2654208

    unsigned short* wpad = (unsigned short*)d_ws;
    unsigned short* hrbf = (unsigned short*)((char*)d_ws + wpad_b);
    unsigned short* lrbf = (unsigned short*)((char*)d_ws + wpad_b + hrbf_b);
    unsigned short* wop  = (unsigned short*)((char*)d_ws + wpad_b + hrbf_b + lrbf_b);
    float*          offw = (float*)((char*)d_ws + wpad_b + hrbf_b + lrbf_b + woff_b);

    const bool full     = ws_size >= wpad_b + hrbf_b + lrbf_b + woff_b + offw_b;
    const bool use_hrbf = ws_size >= wpad_b + hrbf_b + lrbf_b;  // pc2 clamp may read into lrbf

    if (full) {
        prep_kernel<<<5472, 256, 0, stream>>>(hr, lr, w_def, w_off,
                                              hrbf, lrbf, wpad, wop);
        offset_mfma_kernel<<<4*HH, 768, 0, stream>>>(lrbf, hrbf, wop, b_off, offw);
        deform3_kernel<<<4*HH*2, 384, 0, stream>>>(hrbf, wpad, b_def, offw, outp);
    } else {
        wcvt_kernel<<<(CC*NG*KSG + 255)/256, 256, 0, stream>>>(w_def, wpad);
        if (use_hrbf)
            cvt8_kernel<<<(4*NG*PLANE)/256, 256, 0, stream>>>(hr, hrbf);
        offset_conv_kernel<<<4*36*NGRP, 256, 0, stream>>>(lr, hr, w_off, outp);
        if (use_hrbf)
            deform2_kernel<true, false><<<4*HH, 768, 0, stream>>>(
                hr, hrbf, b_off, wpad, b_def, offw, outp);
        else
            deform2_kernel<false, false><<<4*HH, 768, 0, stream>>>(
                hr, hrbf, b_off, wpad, b_def, offw, outp);
    }
}